// Round 1
// baseline (184.818 us; speedup 1.0000x reference)
//
#include <hip/hip_runtime.h>

// fastmax linear attention (causal, p=1): chunked scan formulation.
// b=2, h=8, n=8192, d=32  -> bh=16, chunks of C=64 rows, 128 chunks per bh.
// State per chunk: KV (32x32) + Ksum (32) + Vsum (32) = 1088 floats.

#define D      32
#define C      64
#define NCHUNK 128
#define BH     16
#define NSEQ   8192
#define STATE  1088

// ---------------------------------------------------------------------------
// Kernel 1: per-chunk state sums.  grid = BH*NCHUNK blocks, 256 threads.
// ---------------------------------------------------------------------------
__global__ __launch_bounds__(256) void chunk_state_kernel(
    const float* __restrict__ k, const float* __restrict__ v,
    float* __restrict__ states) {
  int blk = blockIdx.x;
  int bh  = blk >> 7;       // / NCHUNK
  int c   = blk & 127;      // % NCHUNK
  size_t off = ((size_t)bh * NSEQ + (size_t)c * C) * D;
  const float* kp = k + off;
  const float* vp = v + off;

  __shared__ float k_s[C * 33];   // padded stride 33 -> conflict-free column reads
  __shared__ float v_s[C * D];    // unpadded -> aligned float4 reads

  int t = threadIdx.x;
  for (int r = 0; r < 8; ++r) {
    int idx = t + r * 256;        // 0..2047, coalesced
    int j = idx >> 5, e = idx & 31;
    k_s[j * 33 + e] = kp[idx];
    v_s[idx]        = vp[idx];
  }
  __syncthreads();

  // KV[d1][d2] = sum_j k[j][d1] * v[j][d2]; 4 d2-entries per thread.
  int d1 = t >> 3;
  int d2 = (t & 7) * 4;
  float a0 = 0.f, a1 = 0.f, a2 = 0.f, a3 = 0.f;
  for (int j = 0; j < C; ++j) {
    float kk = k_s[j * 33 + d1];
    float4 vv = *(const float4*)&v_s[j * D + d2];
    a0 += kk * vv.x; a1 += kk * vv.y; a2 += kk * vv.z; a3 += kk * vv.w;
  }
  float* st = states + (size_t)blk * STATE;
  *(float4*)&st[d1 * D + d2] = make_float4(a0, a1, a2, a3);

  // K / V column sums (wave 0 tail work)
  if (t < 64) {
    int e = t & 31;
    float s = 0.f;
    if (t < 32) {
      for (int j = 0; j < C; ++j) s += k_s[j * 33 + e];
      st[1024 + e] = s;
    } else {
      for (int j = 0; j < C; ++j) s += v_s[j * D + e];
      st[1056 + e] = s;
    }
  }
}

// ---------------------------------------------------------------------------
// Kernel 2: in-place exclusive prefix scan of chunk states.  grid = BH.
// ---------------------------------------------------------------------------
__global__ __launch_bounds__(256) void scan_kernel(float* __restrict__ states) {
  int bh = blockIdx.x;
  float* base = states + (size_t)bh * NCHUNK * STATE;
  int t = threadIdx.x;
  float a0 = 0.f, a1 = 0.f, a2 = 0.f, a3 = 0.f, a4 = 0.f;
  for (int c = 0; c < NCHUNK; ++c) {
    float* p = base + (size_t)c * STATE;
    float s0 = p[t], s1 = p[t + 256], s2 = p[t + 512], s3 = p[t + 768];
    float s4 = 0.f;
    if (t < 64) s4 = p[t + 1024];
    p[t] = a0; p[t + 256] = a1; p[t + 512] = a2; p[t + 768] = a3;
    if (t < 64) p[t + 1024] = a4;
    a0 += s0; a1 += s1; a2 += s2; a3 += s3; a4 += s4;
  }
}

// ---------------------------------------------------------------------------
// Kernel 3: per-chunk output.  grid = BH*NCHUNK blocks, 256 threads.
// ---------------------------------------------------------------------------
__global__ __launch_bounds__(256) void output_kernel(
    const float* __restrict__ q, const float* __restrict__ k,
    const float* __restrict__ v, const float* __restrict__ states,
    float* __restrict__ out) {
  int blk = blockIdx.x;
  int bh  = blk >> 7;
  int c   = blk & 127;
  size_t off = ((size_t)bh * NSEQ + (size_t)c * C) * D;
  const float* qp = q + off;
  const float* kp = k + off;
  const float* vp = v + off;
  const float* st = states + (size_t)blk * STATE;

  __shared__ float q_s[C * 33];
  __shared__ float k_s[C * 33];
  __shared__ float v_s[C * D];
  __shared__ float kv_s[D * D];
  __shared__ float kpre_s[D];
  __shared__ float vpre_s[D];
  __shared__ float T_s[C * 65];    // stride 65 -> conflict-free row-sum reads
  __shared__ float invdiv_s[C];

  int t = threadIdx.x;
  for (int r = 0; r < 8; ++r) {
    int idx = t + r * 256;
    int j = idx >> 5, e = idx & 31;
    q_s[j * 33 + e] = qp[idx];
    k_s[j * 33 + e] = kp[idx];
    v_s[idx]        = vp[idx];
  }
  for (int r = 0; r < 4; ++r) kv_s[t + r * 256] = st[t + r * 256];
  if (t < 32)      kpre_s[t]      = st[1024 + t];
  else if (t < 64) vpre_s[t - 32] = st[1024 + t];
  __syncthreads();

  // Phase A: T[i][j] = 1 + q_i . k_j for j<=i.  Folded mapping: thread (j,
  // row-pair i) computes either (i,j) [j<=i] or (63-i, 63-j) [j>i] so every
  // lane does exactly one unmasked 32-FMA dot.  Missing: diagonals of rows
  // 32..63 (patched below).  Masked entries are never read (loops are j<=i).
  {
    int j  = t & 63;
    int ib = t >> 6;                  // wave id: i uniform per wave
    for (int r = 0; r < 8; ++r) {
      int i = ib * 8 + r;             // 0..31
      int ii, jj;
      if (j <= i) { ii = i;       jj = j; }
      else        { ii = 63 - i;  jj = 63 - j; }
      float dot = 0.f;
      for (int dd = 0; dd < D; ++dd)
        dot += q_s[ii * 33 + dd] * k_s[jj * 33 + dd];
      T_s[ii * 65 + jj] = 1.f + dot;
    }
    if (t < 32) {                     // diagonals of rows 32..63
      int i = t + 32;
      float dot = 0.f;
      for (int dd = 0; dd < D; ++dd)
        dot += q_s[i * 33 + dd] * k_s[i * 33 + dd];
      T_s[i * 65 + i] = 1.f + dot;
    }
  }
  __syncthreads();

  // Row sums + prefix-dot -> 1/div.  div = c*C + q_i.K_pre + rowsum(T[i])
  // (rowsum already contains the local (i+1) via the "+1" in T).
  if (t < 64) {
    int i = t;
    float rs = 0.f;
    for (int j = 0; j <= i; ++j) rs += T_s[i * 65 + j];
    float dp = 0.f;
    for (int dd = 0; dd < D; ++dd) dp += q_s[i * 33 + dd] * kpre_s[dd];
    invdiv_s[i] = 1.f / ((float)(c * C) + dp + rs);
  }
  __syncthreads();

  // Phase B: out[i][e] = (V_pre[e] + q_i.KV_pre[:,e] + sum_{j<=i} T[i][j]*v[j][e]) / div
  {
    int e  = t & 31;
    int ib = t >> 5;                  // 0..7; i = r*8+ib -> adjacent i per wave
    for (int r = 0; r < 8; ++r) {
      int i = r * 8 + ib;
      float acc = vpre_s[e];
      for (int dd = 0; dd < D; ++dd)
        acc += q_s[i * 33 + dd] * kv_s[dd * D + e];
      for (int j = 0; j <= i; ++j)
        acc += T_s[i * 65 + j] * v_s[j * D + e];
      out[off + (size_t)i * D + e] = acc * invdiv_s[i];
    }
  }
}

// ---------------------------------------------------------------------------
extern "C" void kernel_launch(void* const* d_in, const int* in_sizes, int n_in,
                              void* d_out, int out_size, void* d_ws, size_t ws_size,
                              hipStream_t stream) {
  const float* q = (const float*)d_in[0];
  const float* k = (const float*)d_in[1];
  const float* v = (const float*)d_in[2];
  float* out    = (float*)d_out;
  float* states = (float*)d_ws;   // BH*NCHUNK*STATE*4 B ~= 8.9 MB

  chunk_state_kernel<<<BH * NCHUNK, 256, 0, stream>>>(k, v, states);
  scan_kernel<<<BH, 256, 0, stream>>>(states);
  output_kernel<<<BH * NCHUNK, 256, 0, stream>>>(q, k, v, states, out);
}

// Round 2
// 161.172 us; speedup vs baseline: 1.1467x; 1.1467x over previous
//
#include <hip/hip_runtime.h>

// fastmax linear attention (causal, p=1): chunked scan formulation.
// b=2, h=8, n=8192, d=32  -> bh=16, chunks of C=64 rows, 128 chunks per bh.
// State per chunk: KV (32x32) + Ksum (32) + Vsum (32) = 1088 floats.
// Scan over chunks is two-level: exclusive scan within groups of 16 chunks,
// then exclusive scan of the 8 group totals; output kernel adds the two.

#define D      32
#define C      64
#define NCHUNK 128
#define GSIZE  16
#define NGROUP 8
#define BH     16
#define NSEQ   8192
#define STATE  1088

// ---------------------------------------------------------------------------
// Kernel 1: per-chunk state sums.  grid = BH*NCHUNK blocks, 256 threads.
// ---------------------------------------------------------------------------
__global__ __launch_bounds__(256) void chunk_state_kernel(
    const float* __restrict__ k, const float* __restrict__ v,
    float* __restrict__ states) {
  int blk = blockIdx.x;
  int bh  = blk >> 7;       // / NCHUNK
  int c   = blk & 127;      // % NCHUNK
  size_t off = ((size_t)bh * NSEQ + (size_t)c * C) * D;
  const float* kp = k + off;
  const float* vp = v + off;

  __shared__ float k_s[C * 33];   // padded stride 33 -> conflict-free column reads
  __shared__ float v_s[C * D];    // unpadded -> aligned float4 reads

  int t = threadIdx.x;
  for (int r = 0; r < 8; ++r) {
    int idx = t + r * 256;        // 0..2047, coalesced
    int j = idx >> 5, e = idx & 31;
    k_s[j * 33 + e] = kp[idx];
    v_s[idx]        = vp[idx];
  }
  __syncthreads();

  // KV[d1][d2] = sum_j k[j][d1] * v[j][d2]; 4 d2-entries per thread.
  int d1 = t >> 3;
  int d2 = (t & 7) * 4;
  float a0 = 0.f, a1 = 0.f, a2 = 0.f, a3 = 0.f;
  for (int j = 0; j < C; ++j) {
    float kk = k_s[j * 33 + d1];
    float4 vv = *(const float4*)&v_s[j * D + d2];
    a0 += kk * vv.x; a1 += kk * vv.y; a2 += kk * vv.z; a3 += kk * vv.w;
  }
  float* st = states + (size_t)blk * STATE;
  *(float4*)&st[d1 * D + d2] = make_float4(a0, a1, a2, a3);

  // K / V column sums (wave 0 tail work)
  if (t < 64) {
    int e = t & 31;
    float s = 0.f;
    if (t < 32) {
      for (int j = 0; j < C; ++j) s += k_s[j * 33 + e];
      st[1024 + e] = s;
    } else {
      for (int j = 0; j < C; ++j) s += v_s[j * D + e];
      st[1056 + e] = s;
    }
  }
}

// ---------------------------------------------------------------------------
// Kernel 2a: in-place EXCLUSIVE scan within each group of 16 chunks; writes
// group totals.  grid = BH*NGROUP = 128 blocks, 256 threads.
// ---------------------------------------------------------------------------
__global__ __launch_bounds__(256) void group_scan_kernel(
    float* __restrict__ states, float* __restrict__ totals) {
  int blk = blockIdx.x;            // bh*NGROUP + g
  float* base = states + (size_t)blk * GSIZE * STATE;
  float* tot  = totals + (size_t)blk * STATE;
  int t = threadIdx.x;
  float a0 = 0.f, a1 = 0.f, a2 = 0.f, a3 = 0.f, a4 = 0.f;
  for (int c = 0; c < GSIZE; ++c) {
    float* p = base + (size_t)c * STATE;
    float s0 = p[t], s1 = p[t + 256], s2 = p[t + 512], s3 = p[t + 768];
    float s4 = (t < 64) ? p[t + 1024] : 0.f;
    p[t] = a0; p[t + 256] = a1; p[t + 512] = a2; p[t + 768] = a3;
    if (t < 64) p[t + 1024] = a4;
    a0 += s0; a1 += s1; a2 += s2; a3 += s3; a4 += s4;
  }
  tot[t] = a0; tot[t + 256] = a1; tot[t + 512] = a2; tot[t + 768] = a3;
  if (t < 64) tot[t + 1024] = a4;
}

// ---------------------------------------------------------------------------
// Kernel 2b: in-place EXCLUSIVE scan of group totals over the 8 groups,
// independent per (bh, element).  grid = ceil(BH*STATE/256) = 68 blocks.
// ---------------------------------------------------------------------------
__global__ __launch_bounds__(256) void totals_scan_kernel(float* __restrict__ totals) {
  int gidx = blockIdx.x * 256 + threadIdx.x;   // 0 .. BH*STATE-1
  if (gidx >= BH * STATE) return;
  int bh = gidx / STATE;
  int e  = gidx % STATE;
  float* base = totals + (size_t)bh * NGROUP * STATE + e;
  float a = 0.f;
  for (int g = 0; g < NGROUP; ++g) {
    float s = base[(size_t)g * STATE];
    base[(size_t)g * STATE] = a;
    a += s;
  }
}

// ---------------------------------------------------------------------------
// Kernel 3: per-chunk output.  grid = BH*NCHUNK blocks, 256 threads.
// State prefix = within-group exclusive (states) + group offset (totals).
// ---------------------------------------------------------------------------
__global__ __launch_bounds__(256) void output_kernel(
    const float* __restrict__ q, const float* __restrict__ k,
    const float* __restrict__ v, const float* __restrict__ states,
    const float* __restrict__ totals, float* __restrict__ out) {
  int blk = blockIdx.x;
  int bh  = blk >> 7;
  int c   = blk & 127;
  size_t off = ((size_t)bh * NSEQ + (size_t)c * C) * D;
  const float* qp = q + off;
  const float* kp = k + off;
  const float* vp = v + off;
  const float* st  = states + (size_t)blk * STATE;
  const float* tot = totals + ((size_t)(bh * NGROUP + (c >> 4))) * STATE;

  __shared__ float q_s[C * 33];
  __shared__ float k_s[C * 33];
  __shared__ float v_s[C * D];
  __shared__ float kv_s[D * D];
  __shared__ float kpre_s[D];
  __shared__ float vpre_s[D];
  __shared__ float T_s[C * 65];    // stride 65 -> conflict-free row-sum reads
  __shared__ float invdiv_s[C];

  int t = threadIdx.x;
  for (int r = 0; r < 8; ++r) {
    int idx = t + r * 256;
    int j = idx >> 5, e = idx & 31;
    q_s[j * 33 + e] = qp[idx];
    k_s[j * 33 + e] = kp[idx];
    v_s[idx]        = vp[idx];
  }
  for (int r = 0; r < 4; ++r) kv_s[t + r * 256] = st[t + r * 256] + tot[t + r * 256];
  if (t < 32)      kpre_s[t]      = st[1024 + t] + tot[1024 + t];
  else if (t < 64) vpre_s[t - 32] = st[1024 + t] + tot[1024 + t];
  __syncthreads();

  // Phase A: T[i][j] = 1 + q_i . k_j for j<=i.  Folded mapping: every lane
  // does exactly one unmasked 32-FMA dot; masked entries never read.
  {
    int j  = t & 63;
    int ib = t >> 6;                  // wave id: i uniform per wave
    for (int r = 0; r < 8; ++r) {
      int i = ib * 8 + r;             // 0..31
      int ii, jj;
      if (j <= i) { ii = i;       jj = j; }
      else        { ii = 63 - i;  jj = 63 - j; }
      float dot = 0.f;
      for (int dd = 0; dd < D; ++dd)
        dot += q_s[ii * 33 + dd] * k_s[jj * 33 + dd];
      T_s[ii * 65 + jj] = 1.f + dot;
    }
    if (t < 32) {                     // diagonals of rows 32..63
      int i = t + 32;
      float dot = 0.f;
      for (int dd = 0; dd < D; ++dd)
        dot += q_s[i * 33 + dd] * k_s[i * 33 + dd];
      T_s[i * 65 + i] = 1.f + dot;
    }
  }
  __syncthreads();

  // Row sums + prefix-dot -> 1/div.  div = c*C + q_i.K_pre + rowsum(T[i]).
  if (t < 64) {
    int i = t;
    float rs = 0.f;
    for (int j = 0; j <= i; ++j) rs += T_s[i * 65 + j];
    float dp = 0.f;
    for (int dd = 0; dd < D; ++dd) dp += q_s[i * 33 + dd] * kpre_s[dd];
    invdiv_s[i] = 1.f / ((float)(c * C) + dp + rs);
  }
  __syncthreads();

  // Phase B: out[i][e] = (V_pre[e] + q_i.KV_pre[:,e] + sum_{j<=i} T[i][j]*v[j][e]) / div
  {
    int e  = t & 31;
    int ib = t >> 5;                  // 0..7; i = r*8+ib -> adjacent i per wave
    for (int r = 0; r < 8; ++r) {
      int i = r * 8 + ib;
      float acc = vpre_s[e];
      for (int dd = 0; dd < D; ++dd)
        acc += q_s[i * 33 + dd] * kv_s[dd * D + e];
      for (int j = 0; j <= i; ++j)
        acc += T_s[i * 65 + j] * v_s[j * D + e];
      out[off + (size_t)i * D + e] = acc * invdiv_s[i];
    }
  }
}

// ---------------------------------------------------------------------------
extern "C" void kernel_launch(void* const* d_in, const int* in_sizes, int n_in,
                              void* d_out, int out_size, void* d_ws, size_t ws_size,
                              hipStream_t stream) {
  const float* q = (const float*)d_in[0];
  const float* k = (const float*)d_in[1];
  const float* v = (const float*)d_in[2];
  float* out    = (float*)d_out;
  float* states = (float*)d_ws;                                  // 8.9 MB
  float* totals = states + (size_t)BH * NCHUNK * STATE;          // +0.56 MB

  chunk_state_kernel<<<BH * NCHUNK, 256, 0, stream>>>(k, v, states);
  group_scan_kernel<<<BH * NGROUP, 256, 0, stream>>>(states, totals);
  totals_scan_kernel<<<(BH * STATE + 255) / 256, 256, 0, stream>>>(totals);
  output_kernel<<<BH * NCHUNK, 256, 0, stream>>>(q, k, v, states, totals, out);
}

// Round 3
// 159.107 us; speedup vs baseline: 1.1616x; 1.0130x over previous
//
#include <hip/hip_runtime.h>

// fastmax linear attention (causal, p=1): chunked scan formulation.
// b=2, h=8, n=8192, d=32  -> bh=16, chunks of C=64 rows, 128 chunks per bh.
// State per chunk: KV (32x32) + Ksum (32) + Vsum (32) = 1088 floats.
// Two-level chunk scan; register-tiled output kernel (GEMM-style).

#define D      32
#define C      64
#define NCHUNK 128
#define GSIZE  16
#define NGROUP 8
#define BH     16
#define NSEQ   8192
#define STATE  1088

// ---------------------------------------------------------------------------
// Kernel 1: per-chunk state sums.  grid = BH*NCHUNK blocks, 256 threads.
// ---------------------------------------------------------------------------
__global__ __launch_bounds__(256) void chunk_state_kernel(
    const float* __restrict__ k, const float* __restrict__ v,
    float* __restrict__ states) {
  int blk = blockIdx.x;
  int bh  = blk >> 7;
  int c   = blk & 127;
  size_t off = ((size_t)bh * NSEQ + (size_t)c * C) * D;
  const float* kp = k + off;
  const float* vp = v + off;

  __shared__ __align__(16) float k_s[C * 33];
  __shared__ __align__(16) float v_s[C * D];

  int t = threadIdx.x;
  for (int r = 0; r < 8; ++r) {
    int idx = t + r * 256;
    int j = idx >> 5, e = idx & 31;
    k_s[j * 33 + e] = kp[idx];
    v_s[idx]        = vp[idx];
  }
  __syncthreads();

  int d1 = t >> 3;
  int d2 = (t & 7) * 4;
  float a0 = 0.f, a1 = 0.f, a2 = 0.f, a3 = 0.f;
  for (int j = 0; j < C; ++j) {
    float kk = k_s[j * 33 + d1];
    float4 vv = *(const float4*)&v_s[j * D + d2];
    a0 += kk * vv.x; a1 += kk * vv.y; a2 += kk * vv.z; a3 += kk * vv.w;
  }
  float* st = states + (size_t)blk * STATE;
  *(float4*)&st[d1 * D + d2] = make_float4(a0, a1, a2, a3);

  if (t < 64) {
    int e = t & 31;
    float s = 0.f;
    if (t < 32) {
      for (int j = 0; j < C; ++j) s += k_s[j * 33 + e];
      st[1024 + e] = s;
    } else {
      for (int j = 0; j < C; ++j) s += v_s[j * D + e];
      st[1056 + e] = s;
    }
  }
}

// ---------------------------------------------------------------------------
// Kernel 2a: exclusive scan within each group of 16 chunks + group totals.
// ---------------------------------------------------------------------------
__global__ __launch_bounds__(256) void group_scan_kernel(
    float* __restrict__ states, float* __restrict__ totals) {
  int blk = blockIdx.x;
  float* base = states + (size_t)blk * GSIZE * STATE;
  float* tot  = totals + (size_t)blk * STATE;
  int t = threadIdx.x;
  float a0 = 0.f, a1 = 0.f, a2 = 0.f, a3 = 0.f, a4 = 0.f;
  for (int c = 0; c < GSIZE; ++c) {
    float* p = base + (size_t)c * STATE;
    float s0 = p[t], s1 = p[t + 256], s2 = p[t + 512], s3 = p[t + 768];
    float s4 = (t < 64) ? p[t + 1024] : 0.f;
    p[t] = a0; p[t + 256] = a1; p[t + 512] = a2; p[t + 768] = a3;
    if (t < 64) p[t + 1024] = a4;
    a0 += s0; a1 += s1; a2 += s2; a3 += s3; a4 += s4;
  }
  tot[t] = a0; tot[t + 256] = a1; tot[t + 512] = a2; tot[t + 768] = a3;
  if (t < 64) tot[t + 1024] = a4;
}

// ---------------------------------------------------------------------------
// Kernel 2b: exclusive scan of group totals over the 8 groups.
// ---------------------------------------------------------------------------
__global__ __launch_bounds__(256) void totals_scan_kernel(float* __restrict__ totals) {
  int gidx = blockIdx.x * 256 + threadIdx.x;
  if (gidx >= BH * STATE) return;
  int bh = gidx / STATE;
  int e  = gidx % STATE;
  float* base = totals + (size_t)bh * NGROUP * STATE + e;
  float a = 0.f;
  for (int g = 0; g < NGROUP; ++g) {
    float s = base[(size_t)g * STATE];
    base[(size_t)g * STATE] = a;
    a += s;
  }
}

// ---------------------------------------------------------------------------
// Kernel 3: register-tiled output kernel.  grid = BH*NCHUNK, 256 threads.
//   thread (tx = t&15, ty = t>>4):
//     phase1: 4x4 tile of S = Q.K^T (outer product over dd via qT/kT),
//             masked -> T_s row-major, rowsums via shfl_xor.
//     phase2: 4x2 tile of O = vpre + Q.KV (outer, 32 steps)
//                            + T.V (inner on T rows, triangular bound),
//             tx==0 lanes also fold q.kpre (kv col 32) -> invdiv.
// ---------------------------------------------------------------------------
__global__ __launch_bounds__(256) void output_kernel(
    const float* __restrict__ q, const float* __restrict__ k,
    const float* __restrict__ v, const float* __restrict__ states,
    const float* __restrict__ totals, float* __restrict__ out) {
  int blk = blockIdx.x;
  int bh  = blk >> 7;
  int c   = blk & 127;
  size_t off = ((size_t)bh * NSEQ + (size_t)c * C) * D;
  const float* qp = q + off;
  const float* kp = k + off;
  const float* vp = v + off;
  const float* st  = states + (size_t)blk * STATE;
  const float* tot = totals + ((size_t)(bh * NGROUP + (c >> 4))) * STATE;

  __shared__ __align__(16) float qT[D * 68];     // qT[dd*68+i] = q[i][dd]
  __shared__ __align__(16) float kT[D * 68];     // kT[dd*68+j] = k[j][dd]
  __shared__ __align__(16) float v_s[C * 36];    // v_s[j*36+e]
  __shared__ __align__(16) float kv_s[D * 36];   // kv_s[dd*36+e]; e=32 -> kpre
  __shared__ __align__(16) float T_s[C * 68];    // T_s[i*68+j], 0 for j>i
  __shared__ __align__(16) float vpre_s[D];
  __shared__ __align__(16) float invdiv_s[C];

  int t  = threadIdx.x;
  int tx = t & 15;          // j0 = 4*tx (phase1) / e0 = 2*tx (phase2)
  int ty = t >> 4;          // i0 = 4*ty
  int i0 = 4 * ty;

  // ---- stage global -> LDS (qT/kT transposed: 4-way write conflict, once) --
  for (int r = 0; r < 8; ++r) {
    int idx = t + r * 256;
    int j = idx >> 5, e = idx & 31;
    qT[e * 68 + j]  = qp[idx];
    kT[e * 68 + j]  = kp[idx];
    v_s[j * 36 + e] = vp[idx];
  }
  for (int r = 0; r < 4; ++r) {
    int idx = t + r * 256;
    int dd = idx >> 5, e = idx & 31;
    kv_s[dd * 36 + e] = st[idx] + tot[idx];
  }
  if (t < 32)      kv_s[t * 36 + 32] = st[1024 + t] + tot[1024 + t];       // kpre
  else if (t < 64) vpre_s[t - 32]    = st[1024 + t] + tot[1024 + t];       // vpre
  __syncthreads();

  // ---- phase 1: S tile, mask -> T_s, rowsums ------------------------------
  int j0 = 4 * tx;
  float s[4][4];
#pragma unroll
  for (int ii = 0; ii < 4; ++ii)
#pragma unroll
    for (int jj = 0; jj < 4; ++jj) s[ii][jj] = 0.f;

#pragma unroll
  for (int dd = 0; dd < D; ++dd) {
    float4 a = *(const float4*)&qT[dd * 68 + i0];
    float4 b = *(const float4*)&kT[dd * 68 + j0];
    float av[4] = {a.x, a.y, a.z, a.w};
    float bv[4] = {b.x, b.y, b.z, b.w};
#pragma unroll
    for (int ii = 0; ii < 4; ++ii)
#pragma unroll
      for (int jj = 0; jj < 4; ++jj) s[ii][jj] += av[ii] * bv[jj];
  }

  float rs[4];
#pragma unroll
  for (int ii = 0; ii < 4; ++ii) {
    int i = i0 + ii;
    float4 tr;
    float* trp = &tr.x;
    float rsum = 0.f;
#pragma unroll
    for (int jj = 0; jj < 4; ++jj) {
      float tv = (j0 + jj <= i) ? (1.f + s[ii][jj]) : 0.f;
      trp[jj] = tv;
      rsum += tv;
    }
    *(float4*)&T_s[i * 68 + j0] = tr;
    rs[ii] = rsum;
  }
  // reduce rowsums across the 16 tx lanes (contiguous within a wave)
#pragma unroll
  for (int m = 8; m >= 1; m >>= 1)
#pragma unroll
    for (int ii = 0; ii < 4; ++ii) rs[ii] += __shfl_xor(rs[ii], m);
  __syncthreads();

  // ---- phase 2: O = vpre + Q.KV + T.V, fold q.kpre on tx==0 ---------------
  int e0 = 2 * tx;
  float acc[4][2];
  {
    float vp0 = vpre_s[e0], vp1 = vpre_s[e0 + 1];
#pragma unroll
    for (int ii = 0; ii < 4; ++ii) { acc[ii][0] = vp0; acc[ii][1] = vp1; }
  }
  float dp[4] = {0.f, 0.f, 0.f, 0.f};

#pragma unroll
  for (int dd = 0; dd < D; ++dd) {
    float4 a = *(const float4*)&qT[dd * 68 + i0];
    float av[4] = {a.x, a.y, a.z, a.w};
    float2 b = *(const float2*)&kv_s[dd * 36 + e0];
#pragma unroll
    for (int ii = 0; ii < 4; ++ii) {
      acc[ii][0] += av[ii] * b.x;
      acc[ii][1] += av[ii] * b.y;
    }
    if (tx == 0) {
      float kpre = kv_s[dd * 36 + 32];
#pragma unroll
      for (int ii = 0; ii < 4; ++ii) dp[ii] += av[ii] * kpre;
    }
  }
  if (tx == 0) {
    float base = (float)(c * C);
#pragma unroll
    for (int ii = 0; ii < 4; ++ii)
      invdiv_s[i0 + ii] = 1.f / (base + dp[ii] + rs[ii]);
  }

  // T.V — inner-product on T rows; triangular bound (T zero past i0+3)
  int jmax = i0 + 4;
  for (int jb = 0; jb < jmax; jb += 4) {
    float4 t0 = *(const float4*)&T_s[(i0 + 0) * 68 + jb];
    float4 t1 = *(const float4*)&T_s[(i0 + 1) * 68 + jb];
    float4 t2 = *(const float4*)&T_s[(i0 + 2) * 68 + jb];
    float4 t3 = *(const float4*)&T_s[(i0 + 3) * 68 + jb];
    const float* tp0 = &t0.x;
    const float* tp1 = &t1.x;
    const float* tp2 = &t2.x;
    const float* tp3 = &t3.x;
#pragma unroll
    for (int jj = 0; jj < 4; ++jj) {
      float2 b = *(const float2*)&v_s[(jb + jj) * 36 + e0];
      acc[0][0] += tp0[jj] * b.x; acc[0][1] += tp0[jj] * b.y;
      acc[1][0] += tp1[jj] * b.x; acc[1][1] += tp1[jj] * b.y;
      acc[2][0] += tp2[jj] * b.x; acc[2][1] += tp2[jj] * b.y;
      acc[3][0] += tp3[jj] * b.x; acc[3][1] += tp3[jj] * b.y;
    }
  }
  __syncthreads();

#pragma unroll
  for (int ii = 0; ii < 4; ++ii) {
    float id = invdiv_s[i0 + ii];
    float2 o;
    o.x = acc[ii][0] * id;
    o.y = acc[ii][1] * id;
    *(float2*)&out[off + (size_t)(i0 + ii) * D + e0] = o;
  }
}

// ---------------------------------------------------------------------------
extern "C" void kernel_launch(void* const* d_in, const int* in_sizes, int n_in,
                              void* d_out, int out_size, void* d_ws, size_t ws_size,
                              hipStream_t stream) {
  const float* q = (const float*)d_in[0];
  const float* k = (const float*)d_in[1];
  const float* v = (const float*)d_in[2];
  float* out    = (float*)d_out;
  float* states = (float*)d_ws;                                  // 8.9 MB
  float* totals = states + (size_t)BH * NCHUNK * STATE;          // +0.56 MB

  chunk_state_kernel<<<BH * NCHUNK, 256, 0, stream>>>(k, v, states);
  group_scan_kernel<<<BH * NGROUP, 256, 0, stream>>>(states, totals);
  totals_scan_kernel<<<(BH * STATE + 255) / 256, 256, 0, stream>>>(totals);
  output_kernel<<<BH * NCHUNK, 256, 0, stream>>>(q, k, v, states, totals, out);
}

// Round 4
// 112.527 us; speedup vs baseline: 1.6424x; 1.4139x over previous
//
#include <hip/hip_runtime.h>

// fastmax linear attention (causal, p=1): chunked scan + bf16 MFMA matmuls.
// b=2, h=8, n=8192, d=32 -> bh=16, chunks of C=64 rows, 128 chunks per bh.
// State per chunk: KV (32x32, [d1][d2]) + Ksum (32) + Vsum (32) = 1088 f32.
// Numerator matmuls (S=QK^T, T.V, Q.KV, KV=K^T.V) in bf16 MFMA; the
// denominator (tiny values possible!) is computed entirely in fp32.

#define D      32
#define C      64
#define NCHUNK 128
#define GSIZE  16
#define NGROUP 8
#define BH     16
#define NSEQ   8192
#define STATE  1088

typedef __attribute__((ext_vector_type(8))) short bf16x8;
typedef __attribute__((ext_vector_type(4))) float f32x4;

__device__ __forceinline__ unsigned short f2bf(float x) {
  union { float f; unsigned u; } c; c.f = x;
  unsigned r = (c.u + 0x7FFFu + ((c.u >> 16) & 1u)) >> 16;   // RNE
  return (unsigned short)r;
}

// ---------------------------------------------------------------------------
// Kernel 1: per-chunk state sums via MFMA.  grid = BH*NCHUNK, 256 threads.
// KV = K^T.V (32x32, K=64) as 4 16x16 tiles; ksum/vsum fp32 in registers.
// ---------------------------------------------------------------------------
__global__ __launch_bounds__(256) void chunk_state_kernel(
    const float* __restrict__ k, const float* __restrict__ v,
    float* __restrict__ states) {
  int blk = blockIdx.x;
  int bh  = blk >> 7;
  int c   = blk & 127;
  size_t off = ((size_t)bh * NSEQ + (size_t)c * C) * D;
  const float* kp = k + off;
  const float* vp = v + off;

  __shared__ __align__(16) unsigned short kT[D * 72];  // kT[e][j], stride 72
  __shared__ __align__(16) unsigned short vT[D * 72];  // vT[e][j]
  __shared__ __align__(16) float psK[256];
  __shared__ __align__(16) float psV[256];

  int t = threadIdx.x;
  int e = t & 31;               // fixed column per thread
  float sk = 0.f, sv = 0.f;
  for (int r = 0; r < 8; ++r) {
    int idx = t + r * 256;      // coalesced; j = (t>>5) + 8r, same e
    int j = idx >> 5;
    float kvv = kp[idx], vvv = vp[idx];
    kT[e * 72 + j] = f2bf(kvv);
    vT[e * 72 + j] = f2bf(vvv);
    sk += kvv; sv += vvv;
  }
  psK[t] = sk; psV[t] = sv;
  __syncthreads();

  int lane = t & 63, w = t >> 6;
  int m16 = lane & 15, quad = lane >> 4;
  int mb = w >> 1, nb = w & 1;            // tile (d1-block, d2-block)
  f32x4 acc = {0.f, 0.f, 0.f, 0.f};
#pragma unroll
  for (int kb = 0; kb < 2; ++kb) {        // K=64 in two k-steps
    bf16x8 a = *(const bf16x8*)&kT[(16 * mb + m16) * 72 + kb * 32 + quad * 8];
    bf16x8 b = *(const bf16x8*)&vT[(16 * nb + m16) * 72 + kb * 32 + quad * 8];
    acc = __builtin_amdgcn_mfma_f32_16x16x32_bf16(a, b, acc, 0, 0, 0);
  }
  float* st = states + (size_t)blk * STATE;
#pragma unroll
  for (int reg = 0; reg < 4; ++reg) {     // row=d1, col=d2 -> st[d1*32+d2]
    int d1 = 16 * mb + quad * 4 + reg;
    int d2 = 16 * nb + m16;
    st[d1 * 32 + d2] = acc[reg];
  }
  if (t < 64) {                           // fp32-exact k/v column sums
    int ee = t & 31;
    float s = 0.f;
    if (t < 32) {
#pragma unroll
      for (int g = 0; g < 8; ++g) s += psK[ee + 32 * g];
      st[1024 + ee] = s;
    } else {
#pragma unroll
      for (int g = 0; g < 8; ++g) s += psV[ee + 32 * g];
      st[1056 + ee] = s;
    }
  }
}

// ---------------------------------------------------------------------------
// Kernel 2a: exclusive scan within each group of 16 chunks + group totals.
// ---------------------------------------------------------------------------
__global__ __launch_bounds__(256) void group_scan_kernel(
    float* __restrict__ states, float* __restrict__ totals) {
  int blk = blockIdx.x;
  float* base = states + (size_t)blk * GSIZE * STATE;
  float* tot  = totals + (size_t)blk * STATE;
  int t = threadIdx.x;
  float a0 = 0.f, a1 = 0.f, a2 = 0.f, a3 = 0.f, a4 = 0.f;
  for (int c = 0; c < GSIZE; ++c) {
    float* p = base + (size_t)c * STATE;
    float s0 = p[t], s1 = p[t + 256], s2 = p[t + 512], s3 = p[t + 768];
    float s4 = (t < 64) ? p[t + 1024] : 0.f;
    p[t] = a0; p[t + 256] = a1; p[t + 512] = a2; p[t + 768] = a3;
    if (t < 64) p[t + 1024] = a4;
    a0 += s0; a1 += s1; a2 += s2; a3 += s3; a4 += s4;
  }
  tot[t] = a0; tot[t + 256] = a1; tot[t + 512] = a2; tot[t + 768] = a3;
  if (t < 64) tot[t + 1024] = a4;
}

// ---------------------------------------------------------------------------
// Kernel 2b: exclusive scan of group totals over the 8 groups.
// ---------------------------------------------------------------------------
__global__ __launch_bounds__(256) void totals_scan_kernel(float* __restrict__ totals) {
  int gidx = blockIdx.x * 256 + threadIdx.x;
  if (gidx >= BH * STATE) return;
  int bh = gidx / STATE;
  int e  = gidx % STATE;
  float* base = totals + (size_t)bh * NGROUP * STATE + e;
  float a = 0.f;
  for (int g = 0; g < NGROUP; ++g) {
    float s = base[(size_t)g * STATE];
    base[(size_t)g * STATE] = a;
    a += s;
  }
}

// ---------------------------------------------------------------------------
// Kernel 3: MFMA output kernel.  grid = BH*NCHUNK, 256 threads (4 waves).
// Wave w owns output rows 16w..16w+15.
//   S = Q.K^T (bf16 MFMA, causal mask) -> T=1+S -> Tbf (bf16, LDS)
//   O = Q.KVpre (MFMA) + T.V (MFMA);  epilogue adds vpre, scales by 1/den.
//   den (fp32 only): cN+i+1 + q_i.(kpre + cumsum_local(k)_i) via fp32
//   column-scan of k + per-row fp32 dots.
// ---------------------------------------------------------------------------
__global__ __launch_bounds__(256) void output_kernel(
    const float* __restrict__ q, const float* __restrict__ k,
    const float* __restrict__ v, const float* __restrict__ states,
    const float* __restrict__ totals, float* __restrict__ out) {
  int blk = blockIdx.x;
  int bh  = blk >> 7;
  int c   = blk & 127;
  size_t off = ((size_t)bh * NSEQ + (size_t)c * C) * D;
  const float* qp = q + off;
  const float* kp = k + off;
  const float* vp = v + off;
  const float* st  = states + (size_t)blk * STATE;
  const float* tot = totals + ((size_t)(bh * NGROUP + (c >> 4))) * STATE;

  __shared__ __align__(16) unsigned short qbf[C * 40];    // [i][dd]
  __shared__ __align__(16) unsigned short kbf[C * 40];    // [j][dd]
  __shared__ __align__(16) unsigned short vTbf[D * 72];   // [e][j]
  __shared__ __align__(16) unsigned short kvTbf[D * 40];  // [e][dd]
  __shared__ __align__(16) unsigned short Tbf[C * 72];    // [i][j]
  __shared__ __align__(16) float q_s[C * 36];             // fp32 q rows
  __shared__ __align__(16) float kc_s[C * 36];            // fp32 k -> cumsum+kpre
  __shared__ __align__(16) float gtot[8 * 32];
  __shared__ __align__(16) float kpre_s[D], vpre_s[D], invdiv_s[C];

  int t = threadIdx.x;
  int e = t & 31;

  // ---- staging ------------------------------------------------------------
  for (int z = t; z < (C * 72) / 8; z += 256)   // zero Tbf (masked region read)
    ((uint4*)Tbf)[z] = make_uint4(0, 0, 0, 0);
  for (int r = 0; r < 8; ++r) {
    int idx = t + r * 256;
    int j = idx >> 5;                  // same e per thread
    float qv = qp[idx], kv = kp[idx], vv = vp[idx];
    q_s[j * 36 + e]  = qv;  qbf[j * 40 + e] = f2bf(qv);
    kc_s[j * 36 + e] = kv;  kbf[j * 40 + e] = f2bf(kv);
    vTbf[e * 72 + j] = f2bf(vv);
  }
  for (int r = 0; r < 4; ++r) {
    int idx = t + r * 256;
    int dd = idx >> 5;                 // st is KV[d1][d2], d1-major
    kvTbf[e * 40 + dd] = f2bf(st[idx] + tot[idx]);
  }
  if (t < 32)      kpre_s[t]      = st[1024 + t] + tot[1024 + t];
  else if (t < 64) vpre_s[t - 32] = st[1024 + t] + tot[1024 + t];
  __syncthreads();

  int lane = t & 63, w = t >> 6;
  int m16 = lane & 15, quad = lane >> 4;

  // ---- part 1: S tiles -> Tbf;  scan phase a (per-thread cumsum of 8 rows) -
  const bf16x8 aQ = *(const bf16x8*)&qbf[(16 * w + m16) * 40 + quad * 8];
  for (int jb = 0; jb <= w; ++jb) {
    bf16x8 bK = *(const bf16x8*)&kbf[(16 * jb + m16) * 40 + quad * 8];
    f32x4 cS = {0.f, 0.f, 0.f, 0.f};
    cS = __builtin_amdgcn_mfma_f32_16x16x32_bf16(aQ, bK, cS, 0, 0, 0);
    int jcol = 16 * jb + m16;
#pragma unroll
    for (int reg = 0; reg < 4; ++reg) {
      int i = 16 * w + quad * 4 + reg;
      float tv = (jcol <= i) ? (1.f + cS[reg]) : 0.f;
      Tbf[i * 72 + jcol] = f2bf(tv);
    }
  }
  int rg = t >> 5;                     // row-group 0..7 (rows rg*8..rg*8+7)
  float vals[8];
  {
    float run = 0.f;
#pragma unroll
    for (int r = 0; r < 8; ++r) {
      vals[r] = kc_s[(rg * 8 + r) * 36 + e];
      run += vals[r];
    }
    gtot[rg * 32 + e] = run;
  }
  __syncthreads();

  // ---- part 2: scan phase b (apply group offsets + kpre, write cumsum) ----
  {
    float offv = kpre_s[e];
    for (int g = 0; g < rg; ++g) offv += gtot[g * 32 + e];
    float cacc = offv;
#pragma unroll
    for (int r = 0; r < 8; ++r) {
      cacc += vals[r];
      kc_s[(rg * 8 + r) * 36 + e] = cacc;   // kpre + cumsum_local(k)
    }
  }
  __syncthreads();

  // ---- part 3: fp32 den (wave 0) + O MFMAs (all waves) --------------------
  if (t < 64) {
    int i = t;
    float dp = 0.f;
#pragma unroll
    for (int d4 = 0; d4 < 8; ++d4) {
      float4 qv = *(const float4*)&q_s[i * 36 + 4 * d4];
      float4 kc = *(const float4*)&kc_s[i * 36 + 4 * d4];
      dp += qv.x * kc.x + qv.y * kc.y + qv.z * kc.z + qv.w * kc.w;
    }
    invdiv_s[i] = 1.f / ((float)(c * C + i + 1) + dp);
  }
  f32x4 o0 = {0.f, 0.f, 0.f, 0.f}, o1 = {0.f, 0.f, 0.f, 0.f};
  {
    bf16x8 b0 = *(const bf16x8*)&kvTbf[(m16)      * 40 + quad * 8];
    bf16x8 b1 = *(const bf16x8*)&kvTbf[(16 + m16) * 40 + quad * 8];
    o0 = __builtin_amdgcn_mfma_f32_16x16x32_bf16(aQ, b0, o0, 0, 0, 0);
    o1 = __builtin_amdgcn_mfma_f32_16x16x32_bf16(aQ, b1, o1, 0, 0, 0);
  }
  int kbcnt = (w >= 2) ? 2 : 1;        // T is zero past column 16w+15
  for (int kb = 0; kb < kbcnt; ++kb) {
    bf16x8 aT = *(const bf16x8*)&Tbf[(16 * w + m16) * 72 + kb * 32 + quad * 8];
    bf16x8 b0 = *(const bf16x8*)&vTbf[(m16)      * 72 + kb * 32 + quad * 8];
    bf16x8 b1 = *(const bf16x8*)&vTbf[(16 + m16) * 72 + kb * 32 + quad * 8];
    o0 = __builtin_amdgcn_mfma_f32_16x16x32_bf16(aT, b0, o0, 0, 0, 0);
    o1 = __builtin_amdgcn_mfma_f32_16x16x32_bf16(aT, b1, o1, 0, 0, 0);
  }
  __syncthreads();

  // ---- epilogue -----------------------------------------------------------
#pragma unroll
  for (int reg = 0; reg < 4; ++reg) {
    int i = 16 * w + quad * 4 + reg;
    float id = invdiv_s[i];
    int e0 = m16, e1 = 16 + m16;
    out[off + (size_t)i * D + e0] = (vpre_s[e0] + o0[reg]) * id;
    out[off + (size_t)i * D + e1] = (vpre_s[e1] + o1[reg]) * id;
  }
}

// ---------------------------------------------------------------------------
extern "C" void kernel_launch(void* const* d_in, const int* in_sizes, int n_in,
                              void* d_out, int out_size, void* d_ws, size_t ws_size,
                              hipStream_t stream) {
  const float* q = (const float*)d_in[0];
  const float* k = (const float*)d_in[1];
  const float* v = (const float*)d_in[2];
  float* out    = (float*)d_out;
  float* states = (float*)d_ws;                                  // 8.9 MB
  float* totals = states + (size_t)BH * NCHUNK * STATE;          // +0.56 MB

  chunk_state_kernel<<<BH * NCHUNK, 256, 0, stream>>>(k, v, states);
  group_scan_kernel<<<BH * NGROUP, 256, 0, stream>>>(states, totals);
  totals_scan_kernel<<<(BH * STATE + 255) / 256, 256, 0, stream>>>(totals);
  output_kernel<<<BH * NCHUNK, 256, 0, stream>>>(q, k, v, states, totals, out);
}